// Round 16
// baseline (304.530 us; speedup 1.0000x reference)
//
#include <hip/hip_runtime.h>
#include <hip/hip_bf16.h>
#include <cstdint>

#define HD   256
#define BSZ  4096
#define NFV  131072
#define NRV  262144
#define VV   8001
#define TOPKN 5
#define RBOFF (BSZ + 1)
#define EPAD 8064   // emb rows padded to 63*128

typedef __attribute__((ext_vector_type(8))) short short8v;
typedef __attribute__((ext_vector_type(4))) float float4v;

// ---------------- Threefry-2x32 (JAX-exact, 20 rounds) ----------------
__host__ __device__ __forceinline__ unsigned rotl32(unsigned v, int d) {
  return (v << d) | (v >> (32 - d));
}

__host__ __device__ __forceinline__ void threefry2x32(
    unsigned k0, unsigned k1, unsigned x0, unsigned x1,
    unsigned& o0, unsigned& o1) {
  unsigned ks2 = k0 ^ k1 ^ 0x1BD11BDAu;
  x0 += k0; x1 += k1;
  x0 += x1; x1 = rotl32(x1, 13); x1 ^= x0;
  x0 += x1; x1 = rotl32(x1, 15); x1 ^= x0;
  x0 += x1; x1 = rotl32(x1, 26); x1 ^= x0;
  x0 += x1; x1 = rotl32(x1,  6); x1 ^= x0;
  x0 += k1; x1 += ks2 + 1u;
  x0 += x1; x1 = rotl32(x1, 17); x1 ^= x0;
  x0 += x1; x1 = rotl32(x1, 29); x1 ^= x0;
  x0 += x1; x1 = rotl32(x1, 16); x1 ^= x0;
  x0 += x1; x1 = rotl32(x1, 24); x1 ^= x0;
  x0 += ks2; x1 += k0 + 2u;
  x0 += x1; x1 = rotl32(x1, 13); x1 ^= x0;
  x0 += x1; x1 = rotl32(x1, 15); x1 ^= x0;
  x0 += x1; x1 = rotl32(x1, 26); x1 ^= x0;
  x0 += x1; x1 = rotl32(x1,  6); x1 ^= x0;
  x0 += k0; x1 += k1 + 3u;
  x0 += x1; x1 = rotl32(x1, 17); x1 ^= x0;
  x0 += x1; x1 = rotl32(x1, 29); x1 ^= x0;
  x0 += x1; x1 = rotl32(x1, 16); x1 ^= x0;
  x0 += x1; x1 = rotl32(x1, 24); x1 ^= x0;
  x0 += k1; x1 += ks2 + 4u;
  x0 += x1; x1 = rotl32(x1, 13); x1 ^= x0;
  x0 += x1; x1 = rotl32(x1, 15); x1 ^= x0;
  x0 += x1; x1 = rotl32(x1, 26); x1 ^= x0;
  x0 += x1; x1 = rotl32(x1,  6); x1 ^= x0;
  x0 += ks2; x1 += k0 + 5u;
  o0 = x0; o1 = x1;
}

__device__ __forceinline__ unsigned short f2bf(float f) {
  unsigned u = __float_as_uint(f);
  unsigned r = (u + 0x7FFFu + ((u >> 16) & 1u)) >> 16;  // RNE
  return (unsigned short)r;
}
__device__ __forceinline__ float bf2f(unsigned short s) {
  return __uint_as_float(((unsigned)s) << 16);
}

__device__ __forceinline__ int lower_bound_i(const int* __restrict__ a, int n, int v) {
  int lo = 0, hi = n;
  while (lo < hi) { int m = (lo + hi) >> 1; if (a[m] < v) lo = m + 1; else hi = m; }
  return lo;
}

// async global->LDS, 16B per lane (dest must be wave base + lane*16)
__device__ __forceinline__ void gl16(const unsigned short* g, unsigned short* l) {
  __builtin_amdgcn_global_load_lds(
      (const __attribute__((address_space(1))) unsigned int*)g,
      (__attribute__((address_space(3))) unsigned int*)l, 16, 0, 0);
}

// ---------------- prep: bounds + emb split + w1/w2 transpose+split ----------------
__global__ __launch_bounds__(256) void prep_kernel(
    const int* __restrict__ ab, const int* __restrict__ rb, int* __restrict__ bounds,
    const float* __restrict__ emb, unsigned short* __restrict__ ehi,
    unsigned short* __restrict__ elo,
    const float* __restrict__ w1, unsigned short* __restrict__ w1th,
    unsigned short* __restrict__ w1tl,
    const float* __restrict__ w2, unsigned short* __restrict__ w2th,
    unsigned short* __restrict__ w2tl) {
  int blk = blockIdx.x, t = threadIdx.x;
  if (blk < 33) {
    int i = blk * 256 + t;
    if (i <= BSZ) bounds[i] = lower_bound_i(ab, NFV, i);
    else if (i <= 2 * BSZ + 1) bounds[i] = lower_bound_i(rb, NRV, i - RBOFF);
  } else if (blk < 33 + 2016) {
    size_t i = ((size_t)(blk - 33) * 256 + t) * 4;
    int row = (int)(i >> 8);
    float f[4] = {0.f, 0.f, 0.f, 0.f};
    if (row < VV) {
      float4 v = *reinterpret_cast<const float4*>(&emb[i]);
      f[0] = v.x; f[1] = v.y; f[2] = v.z; f[3] = v.w;
    }
    unsigned short h[4], l[4];
#pragma unroll
    for (int j = 0; j < 4; ++j) {
      h[j] = f2bf(f[j]);
      l[j] = f2bf(f[j] - bf2f(h[j]));
    }
    *reinterpret_cast<uint2*>(&ehi[i]) = *reinterpret_cast<uint2*>(h);
    *reinterpret_cast<uint2*>(&elo[i]) = *reinterpret_cast<uint2*>(l);
  } else if (blk < 33 + 2016 + 768) {
    int i = (blk - 2049) * 256 + t;          // 0..196607
    int n = i / 768, k = i - n * 768;        // w1t[n][k] = w1[k][n]
    float v = w1[k * 256 + n];
    unsigned short h = f2bf(v);
    w1th[i] = h; w1tl[i] = f2bf(v - bf2f(h));
  } else {
    int i = (blk - 2817) * 256 + t;          // 0..65535
    int n = i >> 8, k = i & 255;
    float v = w2[k * 256 + n];
    unsigned short h = f2bf(v);
    w2th[i] = h; w2tl[i] = f2bf(v - bf2f(h));
  }
}

// ---------------- center (bit-identical) + residue mask bytes ----------------
__global__ __launch_bounds__(256) void mask_kernel(
    const float* __restrict__ pcf, const float* __restrict__ rpos,
    const int* __restrict__ bounds, unsigned char* __restrict__ mask) {
  int lane = threadIdx.x & 63;
  int b = blockIdx.x * 4 + (threadIdx.x >> 6);
  int a0 = bounds[b], a1 = bounds[b + 1];
  int r0 = bounds[RBOFF + b], r1 = bounds[RBOFF + b + 1];

  float cp = 0.f;
  if (lane < 3 && a0 < a1) {
    float nv = pcf[(size_t)a0 * 3 + lane];
    for (int aa = a0; aa < a1; ++aa) {
      float cv = nv;
      if (aa + 1 < a1) nv = pcf[(size_t)(aa + 1) * 3 + lane];
      cp += cv;
    }
  }
  if (lane < 3) cp = cp / fmaxf((float)(a1 - a0), 1.0f);
  float cx = __shfl(cp, 0), cy = __shfl(cp, 1), cz = __shfl(cp, 2);

  for (int r = r0 + lane; r < r1; r += 64) {
    float dx = rpos[(size_t)r * 9 + 3] - cx;
    float dy = rpos[(size_t)r * 9 + 4] - cy;
    float dz = rpos[(size_t)r * 9 + 5] - cz;
    mask[r] = (dx * dx + dy * dy + dz * dz < 36.0f) ? 1 : 0;  // == sqrtf<6
  }
}

// ---------------- segment fusion: 2 waves per batch element, LDS combine ----------------
__global__ __launch_bounds__(256) void fuse_seg_kernel(
    const float* __restrict__ hcf, const int* __restrict__ wid,
    const float* __restrict__ hres, const unsigned char* __restrict__ mask,
    const unsigned short* __restrict__ ehi, const unsigned short* __restrict__ elo,
    const int* __restrict__ bounds,
    unsigned short* __restrict__ pvh, unsigned short* __restrict__ pvl) {
  int t = threadIdx.x;
  int lane = t & 63, wv = t >> 6;       // 4 waves
  int half = wv & 1;
  int b = blockIdx.x * 2 + (wv >> 1);
  int a0 = bounds[b], a1 = bounds[b + 1];
  int r0 = bounds[RBOFF + b], r1 = bounds[RBOFF + b + 1];
  size_t off = (size_t)lane * 4;
  size_t o = (size_t)b * 768;

  __shared__ float4v part[4][64];

  // ---- node partial: this wave takes chunks c ≡ half (mod 2) ----
  float4v acc = 0.f;
  for (int c = half;; c += 2) {
    int base = a0 + 8 * c;
    if (base >= a1) break;
    if (base + 8 <= a1) {
      float4v v[8];
#pragma unroll
      for (int j = 0; j < 8; ++j)
        v[j] = *reinterpret_cast<const float4v*>(&hcf[(size_t)(base + j) * HD + off]);
      acc += ((v[0] + v[1]) + (v[2] + v[3])) + ((v[4] + v[5]) + (v[6] + v[7]));
    } else {
      for (int a = base; a < a1; ++a)
        acc += *reinterpret_cast<const float4v*>(&hcf[(size_t)a * HD + off]);
    }
  }
  part[wv][lane] = acc;
  __syncthreads();
  if (half == 0) {
    float4v s = part[wv][lane] + part[wv + 1][lane];
    unsigned short h[4], l[4];
#pragma unroll
    for (int j = 0; j < 4; ++j) {
      h[j] = f2bf(s[j]); l[j] = f2bf(s[j] - bf2f(h[j]));
    }
    *reinterpret_cast<uint2*>(&pvh[o + off]) = *reinterpret_cast<uint2*>(h);
    *reinterpret_cast<uint2*>(&pvl[o + off]) = *reinterpret_cast<uint2*>(l);
  } else {
    *reinterpret_cast<uint2*>(&pvh[o + 256 + off]) =
        *reinterpret_cast<const uint2*>(&ehi[(size_t)wid[b] * 256 + off]);
    *reinterpret_cast<uint2*>(&pvl[o + 256 + off]) =
        *reinterpret_cast<const uint2*>(&elo[(size_t)wid[b] * 256 + off]);
  }
  __syncthreads();   // combine-read done before part is rewritten below

  // ---- residue partial: chunks aligned to 8 for uint2 mask loads ----
  float4v racc = 0.f;
  int ra = (r0 + 7) & ~7;
  if (half == 0) {
    int pe = ra < r1 ? ra : r1;
    for (int r = r0; r < pe; ++r) {
      float4v v = *reinterpret_cast<const float4v*>(&hres[(size_t)r * HD + off]);
      if (mask[r]) racc += v;
    }
  }
  for (int c = half;; c += 2) {
    int base = ra + 8 * c;
    if (base >= r1) break;
    if (base + 8 <= r1) {
      uint2 mw = *reinterpret_cast<const uint2*>(&mask[base]);   // aligned
      float4v v[8];
#pragma unroll
      for (int j = 0; j < 8; ++j)
        v[j] = *reinterpret_cast<const float4v*>(&hres[(size_t)(base + j) * HD + off]);
      float4v s0 = 0.f, s1 = 0.f, s2 = 0.f, s3 = 0.f;
      if (mw.x & 0x000000FFu) s0 += v[0];
      if (mw.x & 0x0000FF00u) s1 += v[1];
      if (mw.x & 0x00FF0000u) s2 += v[2];
      if (mw.x & 0xFF000000u) s3 += v[3];
      if (mw.y & 0x000000FFu) s0 += v[4];
      if (mw.y & 0x0000FF00u) s1 += v[5];
      if (mw.y & 0x00FF0000u) s2 += v[6];
      if (mw.y & 0xFF000000u) s3 += v[7];
      racc += (s0 + s1) + (s2 + s3);
    } else {
      for (int r = base; r < r1; ++r) {
        float4v v = *reinterpret_cast<const float4v*>(&hres[(size_t)r * HD + off]);
        if (mask[r]) racc += v;
      }
    }
  }
  part[wv][lane] = racc;
  __syncthreads();
  if (half == 0) {
    float4v s = part[wv][lane] + part[wv + 1][lane];
    unsigned short h[4], l[4];
#pragma unroll
    for (int j = 0; j < 4; ++j) {
      h[j] = f2bf(s[j]); l[j] = f2bf(s[j] - bf2f(h[j]));
    }
    *reinterpret_cast<uint2*>(&pvh[o + 512 + off]) = *reinterpret_cast<uint2*>(h);
    *reinterpret_cast<uint2*>(&pvl[o + 512 + off]) = *reinterpret_cast<uint2*>(l);
  }
}

// ---------------- MFMA 3-term MLP GEMM, 64x64 tile; bias(+relu) + split write ----------------
template <bool RELU, int K, int N>
__global__ __launch_bounds__(256) void mlp_gemm_kernel(
    const unsigned short* __restrict__ Ahg, const unsigned short* __restrict__ Alg,
    const unsigned short* __restrict__ Bhg, const unsigned short* __restrict__ Blg,
    const float* __restrict__ bias,
    unsigned short* __restrict__ Chi, unsigned short* __restrict__ Clo) {
  __shared__ __attribute__((aligned(16))) unsigned short Ahs[64][72];
  __shared__ __attribute__((aligned(16))) unsigned short Als[64][72];
  __shared__ __attribute__((aligned(16))) unsigned short Bhs[64][72];
  __shared__ __attribute__((aligned(16))) unsigned short Bls[64][72];

  int t = threadIdx.x;
  int bm = blockIdx.y * 64, bn = blockIdx.x * 64;
  int lane = t & 63, wv = t >> 6;
  int wm = wv >> 1, wn = wv & 1;
  int lr = lane & 15, lg = lane >> 4;
  float4v acc[2][2] = {};

  int srow = t >> 2, sc = (t & 3) * 16;

  for (int kb = 0; kb < K; kb += 64) {
    size_t ga = (size_t)(bm + srow) * K + kb + sc;
    size_t gb = (size_t)(bn + srow) * K + kb + sc;
    *reinterpret_cast<short8v*>(&Ahs[srow][sc]) = *reinterpret_cast<const short8v*>(&Ahg[ga]);
    *reinterpret_cast<short8v*>(&Ahs[srow][sc + 8]) = *reinterpret_cast<const short8v*>(&Ahg[ga + 8]);
    *reinterpret_cast<short8v*>(&Als[srow][sc]) = *reinterpret_cast<const short8v*>(&Alg[ga]);
    *reinterpret_cast<short8v*>(&Als[srow][sc + 8]) = *reinterpret_cast<const short8v*>(&Alg[ga + 8]);
    *reinterpret_cast<short8v*>(&Bhs[srow][sc]) = *reinterpret_cast<const short8v*>(&Bhg[gb]);
    *reinterpret_cast<short8v*>(&Bhs[srow][sc + 8]) = *reinterpret_cast<const short8v*>(&Bhg[gb + 8]);
    *reinterpret_cast<short8v*>(&Bls[srow][sc]) = *reinterpret_cast<const short8v*>(&Blg[gb]);
    *reinterpret_cast<short8v*>(&Bls[srow][sc + 8]) = *reinterpret_cast<const short8v*>(&Blg[gb + 8]);
    __syncthreads();

#pragma unroll
    for (int ks = 0; ks < 2; ++ks) {
      int ko = ks * 32 + lg * 8;
      short8v aH[2], aL[2], bH[2], bL[2];
#pragma unroll
      for (int f = 0; f < 2; ++f) {
        aH[f] = *reinterpret_cast<const short8v*>(&Ahs[wm * 32 + f * 16 + lr][ko]);
        aL[f] = *reinterpret_cast<const short8v*>(&Als[wm * 32 + f * 16 + lr][ko]);
        bH[f] = *reinterpret_cast<const short8v*>(&Bhs[wn * 32 + f * 16 + lr][ko]);
        bL[f] = *reinterpret_cast<const short8v*>(&Bls[wn * 32 + f * 16 + lr][ko]);
      }
#pragma unroll
      for (int mf = 0; mf < 2; ++mf)
#pragma unroll
        for (int nf = 0; nf < 2; ++nf) {
          acc[mf][nf] = __builtin_amdgcn_mfma_f32_16x16x32_bf16(
              aH[mf], bH[nf], acc[mf][nf], 0, 0, 0);
          acc[mf][nf] = __builtin_amdgcn_mfma_f32_16x16x32_bf16(
              aH[mf], bL[nf], acc[mf][nf], 0, 0, 0);
          acc[mf][nf] = __builtin_amdgcn_mfma_f32_16x16x32_bf16(
              aL[mf], bH[nf], acc[mf][nf], 0, 0, 0);
        }
    }
    __syncthreads();
  }

#pragma unroll
  for (int mf = 0; mf < 2; ++mf)
#pragma unroll
    for (int nf = 0; nf < 2; ++nf) {
      int col = bn + wn * 32 + nf * 16 + lr;
      float bv = bias[col];
#pragma unroll
      for (int rr = 0; rr < 4; ++rr) {
        int row = bm + wm * 32 + mf * 16 + lg * 4 + rr;
        float v = acc[mf][nf][rr] + bv;
        if (RELU) v = fmaxf(v, 0.f);
        unsigned short h = f2bf(v);
        Chi[(size_t)row * N + col] = h;
        Clo[(size_t)row * N + col] = f2bf(v - bf2f(h));
      }
    }
}

// ---------------- MFMA 3-term score GEMM: 2-phase pipelined, BK=32 dbuf ----------------
// T3 minimum recipe: STAGE(t+1) issued BEFORE compute(t); ONE drain-barrier per
// tile. LDS 64KB (2 bufs x 4 arrays x 8KB), 2 blocks/CU. 64B rows: swizzle
// byte ^= ((row>>1)&3)<<4 both-sides (pre-swizzled source + same XOR on read)
// -> 2-way bank conflict (free).
#define SWZB(row) ((((row) >> 1) & 3) << 4)

__global__ __launch_bounds__(256, 2) void score_gemm_kernel(
    const unsigned short* __restrict__ Ahg, const unsigned short* __restrict__ Alg,
    const unsigned short* __restrict__ Bhg, const unsigned short* __restrict__ Blg,
    float* __restrict__ C) {
  __shared__ __attribute__((aligned(16))) unsigned short Ah[2 * 4096];
  __shared__ __attribute__((aligned(16))) unsigned short Al[2 * 4096];
  __shared__ __attribute__((aligned(16))) unsigned short Bh[2 * 4096];
  __shared__ __attribute__((aligned(16))) unsigned short Bl[2 * 4096];

  int t = threadIdx.x;
  int bm = blockIdx.x * 128;          // x fastest: M-blocks share B-panel in L2
  int bn = blockIdx.y * 128;
  int lane = t & 63, wv = t >> 6;
  int wm = wv >> 1, wn = wv & 1;      // 2x2 waves, each 64x64
  int lr = lane & 15, lg = lane >> 4;

  float4v acc[4][4] = {};

  // staging geometry: tile = 128 rows x 32 shorts (64B). 8KB/array/tile.
  // thread does 2 gl16 per array; dest = wave-uniform base + lane*16B.
  int sidx0 = (wv * 2 + 0) * 512 + lane * 8;   // shorts within tile
  int sidx1 = (wv * 2 + 1) * 512 + lane * 8;
  int srow0 = sidx0 >> 5, srow1 = sidx1 >> 5;
  int scb0 = ((sidx0 & 31) * 2) ^ SWZB(srow0); // pre-swizzled source byte col
  int scb1 = ((sidx1 & 31) * 2) ^ SWZB(srow1);

  auto stage = [&](int kt, int bufb) {
    unsigned base = bufb * 4096;
    size_t gA0 = (size_t)(bm + srow0) * 256 + kt * 32 + (scb0 >> 1);
    size_t gB0 = (size_t)(bn + srow0) * 256 + kt * 32 + (scb0 >> 1);
    size_t gA1 = (size_t)(bm + srow1) * 256 + kt * 32 + (scb1 >> 1);
    size_t gB1 = (size_t)(bn + srow1) * 256 + kt * 32 + (scb1 >> 1);
    gl16(&Ahg[gA0], &Ah[base + sidx0]);
    gl16(&Alg[gA0], &Al[base + sidx0]);
    gl16(&Bhg[gB0], &Bh[base + sidx0]);
    gl16(&Blg[gB0], &Bl[base + sidx0]);
    gl16(&Ahg[gA1], &Ah[base + sidx1]);
    gl16(&Alg[gA1], &Al[base + sidx1]);
    gl16(&Bhg[gB1], &Bh[base + sidx1]);
    gl16(&Blg[gB1], &Bl[base + sidx1]);
  };

  stage(0, 0);
  __syncthreads();                    // drains vmcnt -> buf0 ready

  int bo = lg * 16;                   // byte k-offset within 64B row
  for (int kt = 0; kt < 8; ++kt) {
    int cur = kt & 1;
    if (kt < 7) stage(kt + 1, cur ^ 1);   // loads fly during compute

    unsigned cbase = cur * 8192;      // bytes
    short8v aH[4], aL[4], bH[4], bL[4];
#pragma unroll
    for (int f = 0; f < 4; ++f) {
      int rA = wm * 64 + f * 16 + lr;
      int rB = wn * 64 + f * 16 + lr;
      unsigned oa = cbase + rA * 64 + (bo ^ SWZB(rA));
      unsigned ob = cbase + rB * 64 + (bo ^ SWZB(rB));
      aH[f] = *reinterpret_cast<const short8v*>((const char*)Ah + oa);
      aL[f] = *reinterpret_cast<const short8v*>((const char*)Al + oa);
      bH[f] = *reinterpret_cast<const short8v*>((const char*)Bh + ob);
      bL[f] = *reinterpret_cast<const short8v*>((const char*)Bl + ob);
    }
#pragma unroll
    for (int mf = 0; mf < 4; ++mf)
#pragma unroll
      for (int nf = 0; nf < 4; ++nf) {
        acc[mf][nf] = __builtin_amdgcn_mfma_f32_16x16x32_bf16(
            aH[mf], bH[nf], acc[mf][nf], 0, 0, 0);
        acc[mf][nf] = __builtin_amdgcn_mfma_f32_16x16x32_bf16(
            aH[mf], bL[nf], acc[mf][nf], 0, 0, 0);
        acc[mf][nf] = __builtin_amdgcn_mfma_f32_16x16x32_bf16(
            aL[mf], bH[nf], acc[mf][nf], 0, 0, 0);
      }

    if (kt < 7) __syncthreads();      // single drain-barrier per tile
  }

  // C/D layout: col = lane&15, row = (lane>>4)*4 + reg  [m89]
#pragma unroll
  for (int mf = 0; mf < 4; ++mf)
#pragma unroll
    for (int nf = 0; nf < 4; ++nf) {
      int col = bn + wn * 64 + nf * 16 + lr;
      if (col < VV) {
#pragma unroll
        for (int rr = 0; rr < 4; ++rr) {
          int row = bm + wm * 64 + mf * 16 + lg * 4 + rr;
          C[(size_t)row * VV + col] = acc[mf][nf][rr];
        }
      }
    }
}

// ---------------- single-pass top-5 + threefry pick ----------------
#define BETTER(av, ai, bv, bi) ((av) > (bv) || ((av) == (bv) && (ai) < (bi)))

__global__ __launch_bounds__(256) void topk_kernel(
    const float* __restrict__ scores, float* __restrict__ preds,
    unsigned k1a, unsigned k1b, unsigned k2a, unsigned k2b) {
  int lane = threadIdx.x & 63;
  int row = (blockIdx.x << 2) + (threadIdx.x >> 6);
  const float* s = scores + (size_t)row * VV;

  const float NEG = -__builtin_huge_valf();
  float v0 = NEG, v1 = NEG, v2 = NEG, v3 = NEG, v4 = NEG;
  int i0 = 0x7FFFFFFF, i1 = 0x7FFFFFFF, i2 = 0x7FFFFFFF, i3 = 0x7FFFFFFF, i4 = 0x7FFFFFFF;

  for (int v = lane; v < VV; v += 64) {
    float val = s[v];
    if (BETTER(val, v, v4, i4)) {
      if (BETTER(val, v, v3, i3)) {
        v4 = v3; i4 = i3;
        if (BETTER(val, v, v2, i2)) {
          v3 = v2; i3 = i2;
          if (BETTER(val, v, v1, i1)) {
            v2 = v1; i2 = i1;
            if (BETTER(val, v, v0, i0)) {
              v1 = v0; i1 = i0; v0 = val; i0 = v;
            } else { v1 = val; i1 = v; }
          } else { v2 = val; i2 = v; }
        } else { v3 = val; i3 = v; }
      } else { v4 = val; i4 = v; }
    }
  }

  int sel0, sel1, sel2, sel3, sel4;
#pragma unroll
  for (int p = 0; p < TOPKN; ++p) {
    float bv = v0; int bi = i0;
#pragma unroll
    for (int off = 32; off > 0; off >>= 1) {
      float ov = __shfl_xor(bv, off);
      int   oi = __shfl_xor(bi, off);
      if (BETTER(ov, oi, bv, bi)) { bv = ov; bi = oi; }
    }
    if (p == 0) sel0 = bi; else if (p == 1) sel1 = bi; else if (p == 2) sel2 = bi;
    else if (p == 3) sel3 = bi; else sel4 = bi;
    if (bi == i0) {
      v0 = v1; i0 = i1; v1 = v2; i1 = i2; v2 = v3; i2 = i3; v3 = v4; i3 = i4;
      v4 = NEG; i4 = 0x7FFFFFFF;
    }
  }

  if (lane == 0) {
    unsigned i = (unsigned)row;
    unsigned h0, h1, l0, l1;
    threefry2x32(k1a, k1b, 0u, i, h0, h1);
    threefry2x32(k2a, k2b, 0u, i, l0, l1);
    unsigned idx = (((h0 ^ h1) % 5u) + ((l0 ^ l1) % 5u)) % 5u;
    int pick = (idx == 0) ? sel0 : (idx == 1) ? sel1 : (idx == 2) ? sel2
             : (idx == 3) ? sel3 : sel4;
    preds[row] = (float)pick;
  }
}

extern "C" void kernel_launch(void* const* d_in, const int* in_sizes, int n_in,
                              void* d_out, int out_size, void* d_ws, size_t ws_size,
                              hipStream_t stream) {
  const float* hcf  = (const float*)d_in[0];
  const float* pcf  = (const float*)d_in[1];
  const int*   wid  = (const int*)d_in[2];
  const int*   ab   = (const int*)d_in[3];
  const float* hres = (const float*)d_in[4];
  const float* rpos = (const float*)d_in[5];
  const int*   rb   = (const int*)d_in[6];
  const float* emb  = (const float*)d_in[7];
  const float* w1   = (const float*)d_in[8];
  const float* bb1  = (const float*)d_in[9];
  const float* w2   = (const float*)d_in[10];
  const float* bb2  = (const float*)d_in[11];

  float* out    = (float*)d_out;
  float* scores = out;
  float* preds  = out + (size_t)BSZ * VV;

  // Intermediates in d_out's dead region (all consumed before scores written):
  char* ob = (char*)d_out;
  unsigned short* pvh  = (unsigned short*)(ob);               // 6 MB
  unsigned short* pvl  = (unsigned short*)(ob + 0x600000);    // 6 MB
  unsigned short* hh   = (unsigned short*)(ob + 0xC00000);    // 2 MB
  unsigned short* hl   = (unsigned short*)(ob + 0xE00000);    // 2 MB
  unsigned short* w1th = (unsigned short*)(ob + 0x1000000);   // 384 KB
  unsigned short* w1tl = (unsigned short*)(ob + 0x1060000);   // 384 KB
  unsigned short* w2th = (unsigned short*)(ob + 0x10C0000);   // 128 KB
  unsigned short* w2tl = (unsigned short*)(ob + 0x10E0000);   // 128 KB

  // d_ws:
  char* ws = (char*)d_ws;
  int*            bounds = (int*)(ws);                        // 32 KB
  unsigned char*  mask   = (unsigned char*)(ws + 0x10000);    // 256 KB
  unsigned short* mh_hi  = (unsigned short*)(ws + 0x100000);  // 2 MB
  unsigned short* mh_lo  = (unsigned short*)(ws + 0x300000);  // 2 MB
  unsigned short* emb_hi = (unsigned short*)(ws + 0x500000);  // 4.03 MB
  unsigned short* emb_lo = (unsigned short*)(ws + 0x900000);  // 4.03 MB

  prep_kernel<<<33 + 2016 + 768 + 256, 256, 0, stream>>>(
      ab, rb, bounds, emb, emb_hi, emb_lo, w1, w1th, w1tl, w2, w2th, w2tl);

  mask_kernel<<<BSZ / 4, 256, 0, stream>>>(pcf, rpos, bounds, mask);

  fuse_seg_kernel<<<BSZ / 2, 256, 0, stream>>>(
      hcf, wid, hres, mask, emb_hi, emb_lo, bounds, pvh, pvl);

  mlp_gemm_kernel<true, 768, 256><<<dim3(4, 64), 256, 0, stream>>>(
      pvh, pvl, w1th, w1tl, bb1, hh, hl);
  mlp_gemm_kernel<false, 256, 256><<<dim3(4, 64), 256, 0, stream>>>(
      hh, hl, w2th, w2tl, bb2, mh_hi, mh_lo);

  score_gemm_kernel<<<dim3(BSZ / 128, EPAD / 128), 256, 0, stream>>>(
      mh_hi, mh_lo, emb_hi, emb_lo, scores);

  unsigned k1a, k1b, k2a, k2b;
  threefry2x32(0u, 1u, 0u, 0u, k1a, k1b);
  threefry2x32(0u, 1u, 0u, 1u, k2a, k2b);
  topk_kernel<<<BSZ / 4, 256, 0, stream>>>(scores, preds, k1a, k1b, k2a, k2b);
}

// Round 17
// 296.793 us; speedup vs baseline: 1.0261x; 1.0261x over previous
//
#include <hip/hip_runtime.h>
#include <hip/hip_bf16.h>
#include <cstdint>

#define HD   256
#define BSZ  4096
#define NFV  131072
#define NRV  262144
#define VV   8001
#define TOPKN 5
#define RBOFF (BSZ + 1)
#define EPAD 8064   // emb rows padded to 63*128

typedef __attribute__((ext_vector_type(8))) short short8v;
typedef __attribute__((ext_vector_type(4))) float float4v;

// ---------------- Threefry-2x32 (JAX-exact, 20 rounds) ----------------
__host__ __device__ __forceinline__ unsigned rotl32(unsigned v, int d) {
  return (v << d) | (v >> (32 - d));
}

__host__ __device__ __forceinline__ void threefry2x32(
    unsigned k0, unsigned k1, unsigned x0, unsigned x1,
    unsigned& o0, unsigned& o1) {
  unsigned ks2 = k0 ^ k1 ^ 0x1BD11BDAu;
  x0 += k0; x1 += k1;
  x0 += x1; x1 = rotl32(x1, 13); x1 ^= x0;
  x0 += x1; x1 = rotl32(x1, 15); x1 ^= x0;
  x0 += x1; x1 = rotl32(x1, 26); x1 ^= x0;
  x0 += x1; x1 = rotl32(x1,  6); x1 ^= x0;
  x0 += k1; x1 += ks2 + 1u;
  x0 += x1; x1 = rotl32(x1, 17); x1 ^= x0;
  x0 += x1; x1 = rotl32(x1, 29); x1 ^= x0;
  x0 += x1; x1 = rotl32(x1, 16); x1 ^= x0;
  x0 += x1; x1 = rotl32(x1, 24); x1 ^= x0;
  x0 += ks2; x1 += k0 + 2u;
  x0 += x1; x1 = rotl32(x1, 13); x1 ^= x0;
  x0 += x1; x1 = rotl32(x1, 15); x1 ^= x0;
  x0 += x1; x1 = rotl32(x1, 26); x1 ^= x0;
  x0 += x1; x1 = rotl32(x1,  6); x1 ^= x0;
  x0 += k0; x1 += k1 + 3u;
  x0 += x1; x1 = rotl32(x1, 17); x1 ^= x0;
  x0 += x1; x1 = rotl32(x1, 29); x1 ^= x0;
  x0 += x1; x1 = rotl32(x1, 16); x1 ^= x0;
  x0 += x1; x1 = rotl32(x1, 24); x1 ^= x0;
  x0 += k1; x1 += ks2 + 4u;
  x0 += x1; x1 = rotl32(x1, 13); x1 ^= x0;
  x0 += x1; x1 = rotl32(x1, 15); x1 ^= x0;
  x0 += x1; x1 = rotl32(x1, 26); x1 ^= x0;
  x0 += x1; x1 = rotl32(x1,  6); x1 ^= x0;
  x0 += ks2; x1 += k0 + 5u;
  o0 = x0; o1 = x1;
}

__device__ __forceinline__ unsigned short f2bf(float f) {
  unsigned u = __float_as_uint(f);
  unsigned r = (u + 0x7FFFu + ((u >> 16) & 1u)) >> 16;  // RNE
  return (unsigned short)r;
}
__device__ __forceinline__ float bf2f(unsigned short s) {
  return __uint_as_float(((unsigned)s) << 16);
}

__device__ __forceinline__ int lower_bound_i(const int* __restrict__ a, int n, int v) {
  int lo = 0, hi = n;
  while (lo < hi) { int m = (lo + hi) >> 1; if (a[m] < v) lo = m + 1; else hi = m; }
  return lo;
}

// async global->LDS, 16B per lane (dest must be wave base + lane*16)
__device__ __forceinline__ void gl16(const unsigned short* g, unsigned short* l) {
  __builtin_amdgcn_global_load_lds(
      (const __attribute__((address_space(1))) unsigned int*)g,
      (__attribute__((address_space(3))) unsigned int*)l, 16, 0, 0);
}

// ---------------- prep: bounds + e3 = [bH|bL|bH] + w1/w2 transpose+split ----------------
__global__ __launch_bounds__(256) void prep_kernel(
    const int* __restrict__ ab, const int* __restrict__ rb, int* __restrict__ bounds,
    const float* __restrict__ emb, unsigned short* __restrict__ e3,
    const float* __restrict__ w1, unsigned short* __restrict__ w1th,
    unsigned short* __restrict__ w1tl,
    const float* __restrict__ w2, unsigned short* __restrict__ w2th,
    unsigned short* __restrict__ w2tl) {
  int blk = blockIdx.x, t = threadIdx.x;
  if (blk < 33) {
    int i = blk * 256 + t;
    if (i <= BSZ) bounds[i] = lower_bound_i(ab, NFV, i);
    else if (i <= 2 * BSZ + 1) bounds[i] = lower_bound_i(rb, NRV, i - RBOFF);
  } else if (blk < 33 + 2016) {
    size_t i = ((size_t)(blk - 33) * 256 + t) * 4;   // element over [8064][256]
    int row = (int)(i >> 8), k = (int)(i & 255);
    float f[4] = {0.f, 0.f, 0.f, 0.f};
    if (row < VV) {
      float4 v = *reinterpret_cast<const float4*>(&emb[i]);
      f[0] = v.x; f[1] = v.y; f[2] = v.z; f[3] = v.w;
    }
    unsigned short h[4], l[4];
#pragma unroll
    for (int j = 0; j < 4; ++j) {
      h[j] = f2bf(f[j]);
      l[j] = f2bf(f[j] - bf2f(h[j]));
    }
    size_t base = (size_t)row * 768 + k;
    *reinterpret_cast<uint2*>(&e3[base])       = *reinterpret_cast<uint2*>(h);
    *reinterpret_cast<uint2*>(&e3[base + 256]) = *reinterpret_cast<uint2*>(l);
    *reinterpret_cast<uint2*>(&e3[base + 512]) = *reinterpret_cast<uint2*>(h);
  } else if (blk < 33 + 2016 + 768) {
    int i = (blk - 2049) * 256 + t;          // 0..196607
    int n = i / 768, k = i - n * 768;        // w1t[n][k] = w1[k][n]
    float v = w1[k * 256 + n];
    unsigned short h = f2bf(v);
    w1th[i] = h; w1tl[i] = f2bf(v - bf2f(h));
  } else {
    int i = (blk - 2817) * 256 + t;          // 0..65535
    int n = i >> 8, k = i & 255;
    float v = w2[k * 256 + n];
    unsigned short h = f2bf(v);
    w2th[i] = h; w2tl[i] = f2bf(v - bf2f(h));
  }
}

// ---------------- center (bit-identical) + residue mask bytes ----------------
__global__ __launch_bounds__(256) void mask_kernel(
    const float* __restrict__ pcf, const float* __restrict__ rpos,
    const int* __restrict__ bounds, unsigned char* __restrict__ mask) {
  int lane = threadIdx.x & 63;
  int b = blockIdx.x * 4 + (threadIdx.x >> 6);
  int a0 = bounds[b], a1 = bounds[b + 1];
  int r0 = bounds[RBOFF + b], r1 = bounds[RBOFF + b + 1];

  float cp = 0.f;
  if (lane < 3 && a0 < a1) {
    float nv = pcf[(size_t)a0 * 3 + lane];
    for (int aa = a0; aa < a1; ++aa) {
      float cv = nv;
      if (aa + 1 < a1) nv = pcf[(size_t)(aa + 1) * 3 + lane];
      cp += cv;
    }
  }
  if (lane < 3) cp = cp / fmaxf((float)(a1 - a0), 1.0f);
  float cx = __shfl(cp, 0), cy = __shfl(cp, 1), cz = __shfl(cp, 2);

  for (int r = r0 + lane; r < r1; r += 64) {
    float dx = rpos[(size_t)r * 9 + 3] - cx;
    float dy = rpos[(size_t)r * 9 + 4] - cy;
    float dz = rpos[(size_t)r * 9 + 5] - cz;
    mask[r] = (dx * dx + dy * dy + dz * dz < 36.0f) ? 1 : 0;  // == sqrtf<6
  }
}

// ---------------- segment fusion: 2 waves per batch element, LDS combine ----------------
__global__ __launch_bounds__(256) void fuse_seg_kernel(
    const float* __restrict__ hcf, const int* __restrict__ wid,
    const float* __restrict__ hres, const unsigned char* __restrict__ mask,
    const unsigned short* __restrict__ e3, const int* __restrict__ bounds,
    unsigned short* __restrict__ pvh, unsigned short* __restrict__ pvl) {
  int t = threadIdx.x;
  int lane = t & 63, wv = t >> 6;       // 4 waves
  int half = wv & 1;
  int b = blockIdx.x * 2 + (wv >> 1);
  int a0 = bounds[b], a1 = bounds[b + 1];
  int r0 = bounds[RBOFF + b], r1 = bounds[RBOFF + b + 1];
  size_t off = (size_t)lane * 4;
  size_t o = (size_t)b * 768;

  __shared__ float4v part[4][64];

  // ---- node partial: this wave takes chunks c ≡ half (mod 2) ----
  float4v acc = 0.f;
  for (int c = half;; c += 2) {
    int base = a0 + 8 * c;
    if (base >= a1) break;
    if (base + 8 <= a1) {
      float4v v[8];
#pragma unroll
      for (int j = 0; j < 8; ++j)
        v[j] = *reinterpret_cast<const float4v*>(&hcf[(size_t)(base + j) * HD + off]);
      acc += ((v[0] + v[1]) + (v[2] + v[3])) + ((v[4] + v[5]) + (v[6] + v[7]));
    } else {
      for (int a = base; a < a1; ++a)
        acc += *reinterpret_cast<const float4v*>(&hcf[(size_t)a * HD + off]);
    }
  }
  part[wv][lane] = acc;
  __syncthreads();
  if (half == 0) {
    float4v s = part[wv][lane] + part[wv + 1][lane];
    unsigned short h[4], l[4];
#pragma unroll
    for (int j = 0; j < 4; ++j) {
      h[j] = f2bf(s[j]); l[j] = f2bf(s[j] - bf2f(h[j]));
    }
    *reinterpret_cast<uint2*>(&pvh[o + off]) = *reinterpret_cast<uint2*>(h);
    *reinterpret_cast<uint2*>(&pvl[o + off]) = *reinterpret_cast<uint2*>(l);
  } else {
    *reinterpret_cast<uint2*>(&pvh[o + 256 + off]) =
        *reinterpret_cast<const uint2*>(&e3[(size_t)wid[b] * 768 + off]);
    *reinterpret_cast<uint2*>(&pvl[o + 256 + off]) =
        *reinterpret_cast<const uint2*>(&e3[(size_t)wid[b] * 768 + 256 + off]);
  }
  __syncthreads();   // combine-read done before part is rewritten below

  // ---- residue partial: chunks aligned to 8 for uint2 mask loads ----
  float4v racc = 0.f;
  int ra = (r0 + 7) & ~7;
  if (half == 0) {
    int pe = ra < r1 ? ra : r1;
    for (int r = r0; r < pe; ++r) {
      float4v v = *reinterpret_cast<const float4v*>(&hres[(size_t)r * HD + off]);
      if (mask[r]) racc += v;
    }
  }
  for (int c = half;; c += 2) {
    int base = ra + 8 * c;
    if (base >= r1) break;
    if (base + 8 <= r1) {
      uint2 mw = *reinterpret_cast<const uint2*>(&mask[base]);   // aligned
      float4v v[8];
#pragma unroll
      for (int j = 0; j < 8; ++j)
        v[j] = *reinterpret_cast<const float4v*>(&hres[(size_t)(base + j) * HD + off]);
      float4v s0 = 0.f, s1 = 0.f, s2 = 0.f, s3 = 0.f;
      if (mw.x & 0x000000FFu) s0 += v[0];
      if (mw.x & 0x0000FF00u) s1 += v[1];
      if (mw.x & 0x00FF0000u) s2 += v[2];
      if (mw.x & 0xFF000000u) s3 += v[3];
      if (mw.y & 0x000000FFu) s0 += v[4];
      if (mw.y & 0x0000FF00u) s1 += v[5];
      if (mw.y & 0x00FF0000u) s2 += v[6];
      if (mw.y & 0xFF000000u) s3 += v[7];
      racc += (s0 + s1) + (s2 + s3);
    } else {
      for (int r = base; r < r1; ++r) {
        float4v v = *reinterpret_cast<const float4v*>(&hres[(size_t)r * HD + off]);
        if (mask[r]) racc += v;
      }
    }
  }
  part[wv][lane] = racc;
  __syncthreads();
  if (half == 0) {
    float4v s = part[wv][lane] + part[wv + 1][lane];
    unsigned short h[4], l[4];
#pragma unroll
    for (int j = 0; j < 4; ++j) {
      h[j] = f2bf(s[j]); l[j] = f2bf(s[j] - bf2f(h[j]));
    }
    *reinterpret_cast<uint2*>(&pvh[o + 512 + off]) = *reinterpret_cast<uint2*>(h);
    *reinterpret_cast<uint2*>(&pvl[o + 512 + off]) = *reinterpret_cast<uint2*>(l);
  }
}

// ---------------- MFMA 3-term MLP GEMM, 64x64 tile; bias(+relu) + split write ----------------
// CONCAT: write mh3 = [aH | aH | aL] row-stride 768 (input to K-768 score GEMM).
template <bool RELU, int K, int N, bool CONCAT>
__global__ __launch_bounds__(256) void mlp_gemm_kernel(
    const unsigned short* __restrict__ Ahg, const unsigned short* __restrict__ Alg,
    const unsigned short* __restrict__ Bhg, const unsigned short* __restrict__ Blg,
    const float* __restrict__ bias,
    unsigned short* __restrict__ Chi, unsigned short* __restrict__ Clo) {
  __shared__ __attribute__((aligned(16))) unsigned short Ahs[64][72];
  __shared__ __attribute__((aligned(16))) unsigned short Als[64][72];
  __shared__ __attribute__((aligned(16))) unsigned short Bhs[64][72];
  __shared__ __attribute__((aligned(16))) unsigned short Bls[64][72];

  int t = threadIdx.x;
  int bm = blockIdx.y * 64, bn = blockIdx.x * 64;
  int lane = t & 63, wv = t >> 6;
  int wm = wv >> 1, wn = wv & 1;
  int lr = lane & 15, lg = lane >> 4;
  float4v acc[2][2] = {};

  int srow = t >> 2, sc = (t & 3) * 16;

  for (int kb = 0; kb < K; kb += 64) {
    size_t ga = (size_t)(bm + srow) * K + kb + sc;
    size_t gb = (size_t)(bn + srow) * K + kb + sc;
    *reinterpret_cast<short8v*>(&Ahs[srow][sc]) = *reinterpret_cast<const short8v*>(&Ahg[ga]);
    *reinterpret_cast<short8v*>(&Ahs[srow][sc + 8]) = *reinterpret_cast<const short8v*>(&Ahg[ga + 8]);
    *reinterpret_cast<short8v*>(&Als[srow][sc]) = *reinterpret_cast<const short8v*>(&Alg[ga]);
    *reinterpret_cast<short8v*>(&Als[srow][sc + 8]) = *reinterpret_cast<const short8v*>(&Alg[ga + 8]);
    *reinterpret_cast<short8v*>(&Bhs[srow][sc]) = *reinterpret_cast<const short8v*>(&Bhg[gb]);
    *reinterpret_cast<short8v*>(&Bhs[srow][sc + 8]) = *reinterpret_cast<const short8v*>(&Bhg[gb + 8]);
    *reinterpret_cast<short8v*>(&Bls[srow][sc]) = *reinterpret_cast<const short8v*>(&Blg[gb]);
    *reinterpret_cast<short8v*>(&Bls[srow][sc + 8]) = *reinterpret_cast<const short8v*>(&Blg[gb + 8]);
    __syncthreads();

#pragma unroll
    for (int ks = 0; ks < 2; ++ks) {
      int ko = ks * 32 + lg * 8;
      short8v aH[2], aL[2], bH[2], bL[2];
#pragma unroll
      for (int f = 0; f < 2; ++f) {
        aH[f] = *reinterpret_cast<const short8v*>(&Ahs[wm * 32 + f * 16 + lr][ko]);
        aL[f] = *reinterpret_cast<const short8v*>(&Als[wm * 32 + f * 16 + lr][ko]);
        bH[f] = *reinterpret_cast<const short8v*>(&Bhs[wn * 32 + f * 16 + lr][ko]);
        bL[f] = *reinterpret_cast<const short8v*>(&Bls[wn * 32 + f * 16 + lr][ko]);
      }
#pragma unroll
      for (int mf = 0; mf < 2; ++mf)
#pragma unroll
        for (int nf = 0; nf < 2; ++nf) {
          acc[mf][nf] = __builtin_amdgcn_mfma_f32_16x16x32_bf16(
              aH[mf], bH[nf], acc[mf][nf], 0, 0, 0);
          acc[mf][nf] = __builtin_amdgcn_mfma_f32_16x16x32_bf16(
              aH[mf], bL[nf], acc[mf][nf], 0, 0, 0);
          acc[mf][nf] = __builtin_amdgcn_mfma_f32_16x16x32_bf16(
              aL[mf], bH[nf], acc[mf][nf], 0, 0, 0);
        }
    }
    __syncthreads();
  }

#pragma unroll
  for (int mf = 0; mf < 2; ++mf)
#pragma unroll
    for (int nf = 0; nf < 2; ++nf) {
      int col = bn + wn * 32 + nf * 16 + lr;
      float bv = bias[col];
#pragma unroll
      for (int rr = 0; rr < 4; ++rr) {
        int row = bm + wm * 32 + mf * 16 + lg * 4 + rr;
        float v = acc[mf][nf][rr] + bv;
        if (RELU) v = fmaxf(v, 0.f);
        unsigned short h = f2bf(v);
        unsigned short l = f2bf(v - bf2f(h));
        if (CONCAT) {
          size_t base = (size_t)row * 768 + col;
          Chi[base] = h; Chi[base + 256] = h; Chi[base + 512] = l;
        } else {
          Chi[(size_t)row * N + col] = h;
          Clo[(size_t)row * N + col] = l;
        }
      }
    }
}

// ---------------- score GEMM: m97 shape, K=768 concat, 2 arrays, 32KB LDS ----------------
// scores = mh3 @ e3^T with mh3=[aH|aH|aL], e3=[bH|bL|bH]: exact 3-term math.
// Linear gl16 dest + pre-swizzled global source + same XOR on ds_read (rule #21).
__global__ __launch_bounds__(256, 3) void score_gemm_kernel(
    const unsigned short* __restrict__ A3, const unsigned short* __restrict__ B3,
    float* __restrict__ C) {
  __shared__ __attribute__((aligned(16))) unsigned short As[128 * 64];
  __shared__ __attribute__((aligned(16))) unsigned short Bs[128 * 64];

  int t = threadIdx.x;
  int bm = blockIdx.x * 128;          // x fastest: M-blocks share B-panel in L2
  int bn = blockIdx.y * 128;
  int lane = t & 63, wv = t >> 6;
  int wm = wv >> 1, wn = wv & 1;      // 2x2 waves, each 64x64
  int lr = lane & 15, lg = lane >> 4;

  float4v acc[4][4] = {};

  int rsub = lane >> 3;               // row within 8-row chunk
  int cb = (lane & 7) * 16;           // byte col within 128B row slice

  for (int kb = 0; kb < 768; kb += 64) {
#pragma unroll
    for (int j = 0; j < 4; ++j) {
      int ch = wv * 4 + j;                       // 16 chunks of 8 rows
      int grow = ch * 8 + rsub;
      int scb = cb ^ ((grow & 7) << 4);          // pre-swizzled source col (bytes)
      size_t goA = (size_t)(bm + grow) * 768 + kb + (scb >> 1);
      size_t goB = (size_t)(bn + grow) * 768 + kb + (scb >> 1);
      unsigned lo = ch * 512 + lane * 8;         // linear dest
      gl16(&A3[goA], &As[lo]);
      gl16(&B3[goB], &Bs[lo]);
    }
    __syncthreads();

#pragma unroll
    for (int ks = 0; ks < 2; ++ks) {
      int bo = (ks * 32 + lg * 8) * 2;           // byte offset within row
      short8v aF[4], bF[4];
#pragma unroll
      for (int f = 0; f < 4; ++f) {
        int rA = wm * 64 + f * 16 + lr;
        int rB = wn * 64 + f * 16 + lr;
        aF[f] = *reinterpret_cast<const short8v*>(
            (const char*)As + rA * 128 + (bo ^ ((rA & 7) << 4)));
        bF[f] = *reinterpret_cast<const short8v*>(
            (const char*)Bs + rB * 128 + (bo ^ ((rB & 7) << 4)));
      }
#pragma unroll
      for (int mf = 0; mf < 4; ++mf)
#pragma unroll
        for (int nf = 0; nf < 4; ++nf)
          acc[mf][nf] = __builtin_amdgcn_mfma_f32_16x16x32_bf16(
              aF[mf], bF[nf], acc[mf][nf], 0, 0, 0);
    }
    __syncthreads();
  }

  // C/D layout: col = lane&15, row = (lane>>4)*4 + reg  [m89]
#pragma unroll
  for (int mf = 0; mf < 4; ++mf)
#pragma unroll
    for (int nf = 0; nf < 4; ++nf) {
      int col = bn + wn * 64 + nf * 16 + lr;
      if (col < VV) {
#pragma unroll
        for (int rr = 0; rr < 4; ++rr) {
          int row = bm + wm * 64 + mf * 16 + lg * 4 + rr;
          C[(size_t)row * VV + col] = acc[mf][nf][rr];
        }
      }
    }
}

// ---------------- single-pass top-5 + threefry pick ----------------
#define BETTER(av, ai, bv, bi) ((av) > (bv) || ((av) == (bv) && (ai) < (bi)))

__global__ __launch_bounds__(256) void topk_kernel(
    const float* __restrict__ scores, float* __restrict__ preds,
    unsigned k1a, unsigned k1b, unsigned k2a, unsigned k2b) {
  int lane = threadIdx.x & 63;
  int row = (blockIdx.x << 2) + (threadIdx.x >> 6);
  const float* s = scores + (size_t)row * VV;

  const float NEG = -__builtin_huge_valf();
  float v0 = NEG, v1 = NEG, v2 = NEG, v3 = NEG, v4 = NEG;
  int i0 = 0x7FFFFFFF, i1 = 0x7FFFFFFF, i2 = 0x7FFFFFFF, i3 = 0x7FFFFFFF, i4 = 0x7FFFFFFF;

  for (int v = lane; v < VV; v += 64) {
    float val = s[v];
    if (BETTER(val, v, v4, i4)) {
      if (BETTER(val, v, v3, i3)) {
        v4 = v3; i4 = i3;
        if (BETTER(val, v, v2, i2)) {
          v3 = v2; i3 = i2;
          if (BETTER(val, v, v1, i1)) {
            v2 = v1; i2 = i1;
            if (BETTER(val, v, v0, i0)) {
              v1 = v0; i1 = i0; v0 = val; i0 = v;
            } else { v1 = val; i1 = v; }
          } else { v2 = val; i2 = v; }
        } else { v3 = val; i3 = v; }
      } else { v4 = val; i4 = v; }
    }
  }

  int sel0, sel1, sel2, sel3, sel4;
#pragma unroll
  for (int p = 0; p < TOPKN; ++p) {
    float bv = v0; int bi = i0;
#pragma unroll
    for (int off = 32; off > 0; off >>= 1) {
      float ov = __shfl_xor(bv, off);
      int   oi = __shfl_xor(bi, off);
      if (BETTER(ov, oi, bv, bi)) { bv = ov; bi = oi; }
    }
    if (p == 0) sel0 = bi; else if (p == 1) sel1 = bi; else if (p == 2) sel2 = bi;
    else if (p == 3) sel3 = bi; else sel4 = bi;
    if (bi == i0) {
      v0 = v1; i0 = i1; v1 = v2; i1 = i2; v2 = v3; i2 = i3; v3 = v4; i3 = i4;
      v4 = NEG; i4 = 0x7FFFFFFF;
    }
  }

  if (lane == 0) {
    unsigned i = (unsigned)row;
    unsigned h0, h1, l0, l1;
    threefry2x32(k1a, k1b, 0u, i, h0, h1);
    threefry2x32(k2a, k2b, 0u, i, l0, l1);
    unsigned idx = (((h0 ^ h1) % 5u) + ((l0 ^ l1) % 5u)) % 5u;
    int pick = (idx == 0) ? sel0 : (idx == 1) ? sel1 : (idx == 2) ? sel2
             : (idx == 3) ? sel3 : sel4;
    preds[row] = (float)pick;
  }
}

extern "C" void kernel_launch(void* const* d_in, const int* in_sizes, int n_in,
                              void* d_out, int out_size, void* d_ws, size_t ws_size,
                              hipStream_t stream) {
  const float* hcf  = (const float*)d_in[0];
  const float* pcf  = (const float*)d_in[1];
  const int*   wid  = (const int*)d_in[2];
  const int*   ab   = (const int*)d_in[3];
  const float* hres = (const float*)d_in[4];
  const float* rpos = (const float*)d_in[5];
  const int*   rb   = (const int*)d_in[6];
  const float* emb  = (const float*)d_in[7];
  const float* w1   = (const float*)d_in[8];
  const float* bb1  = (const float*)d_in[9];
  const float* w2   = (const float*)d_in[10];
  const float* bb2  = (const float*)d_in[11];

  float* out    = (float*)d_out;
  float* scores = out;
  float* preds  = out + (size_t)BSZ * VV;

  // Intermediates in d_out's dead region (all consumed before scores written):
  char* ob = (char*)d_out;
  unsigned short* pvh  = (unsigned short*)(ob);               // 6 MB
  unsigned short* pvl  = (unsigned short*)(ob + 0x600000);    // 6 MB
  unsigned short* hh   = (unsigned short*)(ob + 0xC00000);    // 2 MB
  unsigned short* hl   = (unsigned short*)(ob + 0xE00000);    // 2 MB
  unsigned short* w1th = (unsigned short*)(ob + 0x1000000);   // 384 KB
  unsigned short* w1tl = (unsigned short*)(ob + 0x1060000);   // 384 KB
  unsigned short* w2th = (unsigned short*)(ob + 0x10C0000);   // 128 KB
  unsigned short* w2tl = (unsigned short*)(ob + 0x10E0000);   // 128 KB

  // d_ws:
  char* ws = (char*)d_ws;
  int*            bounds = (int*)(ws);                        // 32 KB
  unsigned char*  mask   = (unsigned char*)(ws + 0x10000);    // 256 KB
  unsigned short* mh3    = (unsigned short*)(ws + 0x100000);  // 6 MB  [4096][768]
  unsigned short* e3     = (unsigned short*)(ws + 0x700000);  // 11.8 MB [8064][768]

  prep_kernel<<<33 + 2016 + 768 + 256, 256, 0, stream>>>(
      ab, rb, bounds, emb, e3, w1, w1th, w1tl, w2, w2th, w2tl);

  mask_kernel<<<BSZ / 4, 256, 0, stream>>>(pcf, rpos, bounds, mask);

  fuse_seg_kernel<<<BSZ / 2, 256, 0, stream>>>(
      hcf, wid, hres, mask, e3, bounds, pvh, pvl);

  mlp_gemm_kernel<true, 768, 256, false><<<dim3(4, 64), 256, 0, stream>>>(
      pvh, pvl, w1th, w1tl, bb1, hh, hl);
  mlp_gemm_kernel<false, 256, 256, true><<<dim3(4, 64), 256, 0, stream>>>(
      hh, hl, w2th, w2tl, bb2, mh3, nullptr);

  score_gemm_kernel<<<dim3(BSZ / 128, EPAD / 128), 256, 0, stream>>>(mh3, e3, scores);

  unsigned k1a, k1b, k2a, k2b;
  threefry2x32(0u, 1u, 0u, 0u, k1a, k1b);
  threefry2x32(0u, 1u, 0u, 1u, k2a, k2b);
  topk_kernel<<<BSZ / 4, 256, 0, stream>>>(scores, preds, k1a, k1b, k2a, k2b);
}

// Round 18
// 278.856 us; speedup vs baseline: 1.0921x; 1.0643x over previous
//
#include <hip/hip_runtime.h>
#include <hip/hip_bf16.h>
#include <cstdint>

#define HD   256
#define BSZ  4096
#define NFV  131072
#define NRV  262144
#define VV   8001
#define TOPKN 5
#define RBOFF (BSZ + 1)
#define EPAD 8064   // emb rows padded to 63*128

typedef __attribute__((ext_vector_type(8))) short short8v;
typedef __attribute__((ext_vector_type(4))) float float4v;

// ---------------- Threefry-2x32 (JAX-exact, 20 rounds) ----------------
__host__ __device__ __forceinline__ unsigned rotl32(unsigned v, int d) {
  return (v << d) | (v >> (32 - d));
}

__host__ __device__ __forceinline__ void threefry2x32(
    unsigned k0, unsigned k1, unsigned x0, unsigned x1,
    unsigned& o0, unsigned& o1) {
  unsigned ks2 = k0 ^ k1 ^ 0x1BD11BDAu;
  x0 += k0; x1 += k1;
  x0 += x1; x1 = rotl32(x1, 13); x1 ^= x0;
  x0 += x1; x1 = rotl32(x1, 15); x1 ^= x0;
  x0 += x1; x1 = rotl32(x1, 26); x1 ^= x0;
  x0 += x1; x1 = rotl32(x1,  6); x1 ^= x0;
  x0 += k1; x1 += ks2 + 1u;
  x0 += x1; x1 = rotl32(x1, 17); x1 ^= x0;
  x0 += x1; x1 = rotl32(x1, 29); x1 ^= x0;
  x0 += x1; x1 = rotl32(x1, 16); x1 ^= x0;
  x0 += x1; x1 = rotl32(x1, 24); x1 ^= x0;
  x0 += ks2; x1 += k0 + 2u;
  x0 += x1; x1 = rotl32(x1, 13); x1 ^= x0;
  x0 += x1; x1 = rotl32(x1, 15); x1 ^= x0;
  x0 += x1; x1 = rotl32(x1, 26); x1 ^= x0;
  x0 += x1; x1 = rotl32(x1,  6); x1 ^= x0;
  x0 += k0; x1 += k1 + 3u;
  x0 += x1; x1 = rotl32(x1, 17); x1 ^= x0;
  x0 += x1; x1 = rotl32(x1, 29); x1 ^= x0;
  x0 += x1; x1 = rotl32(x1, 16); x1 ^= x0;
  x0 += x1; x1 = rotl32(x1, 24); x1 ^= x0;
  x0 += k1; x1 += ks2 + 4u;
  x0 += x1; x1 = rotl32(x1, 13); x1 ^= x0;
  x0 += x1; x1 = rotl32(x1, 15); x1 ^= x0;
  x0 += x1; x1 = rotl32(x1, 26); x1 ^= x0;
  x0 += x1; x1 = rotl32(x1,  6); x1 ^= x0;
  x0 += ks2; x1 += k0 + 5u;
  o0 = x0; o1 = x1;
}

__device__ __forceinline__ unsigned short f2bf(float f) {
  unsigned u = __float_as_uint(f);
  unsigned r = (u + 0x7FFFu + ((u >> 16) & 1u)) >> 16;  // RNE
  return (unsigned short)r;
}
__device__ __forceinline__ float bf2f(unsigned short s) {
  return __uint_as_float(((unsigned)s) << 16);
}

__device__ __forceinline__ int lower_bound_i(const int* __restrict__ a, int n, int v) {
  int lo = 0, hi = n;
  while (lo < hi) { int m = (lo + hi) >> 1; if (a[m] < v) lo = m + 1; else hi = m; }
  return lo;
}

// async global->LDS, 16B per lane (dest must be wave base + lane*16)
__device__ __forceinline__ void gl16(const unsigned short* g, unsigned short* l) {
  __builtin_amdgcn_global_load_lds(
      (const __attribute__((address_space(1))) unsigned int*)g,
      (__attribute__((address_space(3))) unsigned int*)l, 16, 0, 0);
}

// ---------------- prep: bounds + emb split + w1/w2 transpose+split ----------------
__global__ __launch_bounds__(256) void prep_kernel(
    const int* __restrict__ ab, const int* __restrict__ rb, int* __restrict__ bounds,
    const float* __restrict__ emb, unsigned short* __restrict__ ehi,
    unsigned short* __restrict__ elo,
    const float* __restrict__ w1, unsigned short* __restrict__ w1th,
    unsigned short* __restrict__ w1tl,
    const float* __restrict__ w2, unsigned short* __restrict__ w2th,
    unsigned short* __restrict__ w2tl) {
  int blk = blockIdx.x, t = threadIdx.x;
  if (blk < 33) {
    int i = blk * 256 + t;
    if (i <= BSZ) bounds[i] = lower_bound_i(ab, NFV, i);
    else if (i <= 2 * BSZ + 1) bounds[i] = lower_bound_i(rb, NRV, i - RBOFF);
  } else if (blk < 33 + 2016) {
    size_t i = ((size_t)(blk - 33) * 256 + t) * 4;
    int row = (int)(i >> 8);
    float f[4] = {0.f, 0.f, 0.f, 0.f};
    if (row < VV) {
      float4 v = *reinterpret_cast<const float4*>(&emb[i]);
      f[0] = v.x; f[1] = v.y; f[2] = v.z; f[3] = v.w;
    }
    unsigned short h[4], l[4];
#pragma unroll
    for (int j = 0; j < 4; ++j) {
      h[j] = f2bf(f[j]);
      l[j] = f2bf(f[j] - bf2f(h[j]));
    }
    *reinterpret_cast<uint2*>(&ehi[i]) = *reinterpret_cast<uint2*>(h);
    *reinterpret_cast<uint2*>(&elo[i]) = *reinterpret_cast<uint2*>(l);
  } else if (blk < 33 + 2016 + 768) {
    int i = (blk - 2049) * 256 + t;          // 0..196607
    int n = i / 768, k = i - n * 768;        // w1t[n][k] = w1[k][n]
    float v = w1[k * 256 + n];
    unsigned short h = f2bf(v);
    w1th[i] = h; w1tl[i] = f2bf(v - bf2f(h));
  } else {
    int i = (blk - 2817) * 256 + t;          // 0..65535
    int n = i >> 8, k = i & 255;
    float v = w2[k * 256 + n];
    unsigned short h = f2bf(v);
    w2th[i] = h; w2tl[i] = f2bf(v - bf2f(h));
  }
}

// ---------------- center (bit-identical) + residue mask bytes ----------------
__global__ __launch_bounds__(256) void mask_kernel(
    const float* __restrict__ pcf, const float* __restrict__ rpos,
    const int* __restrict__ bounds, unsigned char* __restrict__ mask) {
  int lane = threadIdx.x & 63;
  int b = blockIdx.x * 4 + (threadIdx.x >> 6);
  int a0 = bounds[b], a1 = bounds[b + 1];
  int r0 = bounds[RBOFF + b], r1 = bounds[RBOFF + b + 1];

  float cp = 0.f;
  if (lane < 3 && a0 < a1) {
    float nv = pcf[(size_t)a0 * 3 + lane];
    for (int aa = a0; aa < a1; ++aa) {
      float cv = nv;
      if (aa + 1 < a1) nv = pcf[(size_t)(aa + 1) * 3 + lane];
      cp += cv;
    }
  }
  if (lane < 3) cp = cp / fmaxf((float)(a1 - a0), 1.0f);
  float cx = __shfl(cp, 0), cy = __shfl(cp, 1), cz = __shfl(cp, 2);

  for (int r = r0 + lane; r < r1; r += 64) {
    float dx = rpos[(size_t)r * 9 + 3] - cx;
    float dy = rpos[(size_t)r * 9 + 4] - cy;
    float dz = rpos[(size_t)r * 9 + 5] - cz;
    mask[r] = (dx * dx + dy * dy + dz * dz < 36.0f) ? 1 : 0;  // == sqrtf<6
  }
}

// ---------------- segment fusion: chunk-pipelined streaming sums ----------------
__global__ __launch_bounds__(256) void fuse_seg_kernel(
    const float* __restrict__ hcf, const int* __restrict__ wid,
    const float* __restrict__ hres, const unsigned char* __restrict__ mask,
    const unsigned short* __restrict__ ehi, const unsigned short* __restrict__ elo,
    const int* __restrict__ bounds,
    unsigned short* __restrict__ pvh, unsigned short* __restrict__ pvl) {
  int lane = threadIdx.x & 63;
  int b = blockIdx.x * 4 + (threadIdx.x >> 6);
  int a0 = bounds[b], a1 = bounds[b + 1];
  int r0 = bounds[RBOFF + b], r1 = bounds[RBOFF + b + 1];
  size_t off = (size_t)lane * 4;

  // node sum: 8-row chunks, double-buffered (issue chunk c+1 before consuming c)
  float4v acc = 0.f;
  int a = a0;
  {
    int nfull = (a1 - a0) >> 3;
    if (nfull > 0) {
      float4v cur[8], nxt[8];
#pragma unroll
      for (int j = 0; j < 8; ++j)
        cur[j] = *reinterpret_cast<const float4v*>(&hcf[(size_t)(a + j) * HD + off]);
      a += 8;
      for (int c = 1; c < nfull; ++c) {
#pragma unroll
        for (int j = 0; j < 8; ++j)
          nxt[j] = *reinterpret_cast<const float4v*>(&hcf[(size_t)(a + j) * HD + off]);
        a += 8;
        acc += ((cur[0] + cur[1]) + (cur[2] + cur[3])) +
               ((cur[4] + cur[5]) + (cur[6] + cur[7]));
#pragma unroll
        for (int j = 0; j < 8; ++j) cur[j] = nxt[j];
      }
      acc += ((cur[0] + cur[1]) + (cur[2] + cur[3])) +
             ((cur[4] + cur[5]) + (cur[6] + cur[7]));
    }
    for (; a < a1; ++a)
      acc += *reinterpret_cast<const float4v*>(&hcf[(size_t)a * HD + off]);
  }

  // residue sum: same chunk pipeline + prefetched mask word
  float4v racc = 0.f;
  int r = r0;
  for (; r < r1 && (r & 7); ++r) {
    float4v v = *reinterpret_cast<const float4v*>(&hres[(size_t)r * HD + off]);
    if (mask[r]) racc += v;
  }
  {
    int nfull = (r1 - r) >> 3;
    if (nfull > 0) {
      float4v cur[8], nxt[8];
      uint2 mcur, mnxt;
      mcur = *reinterpret_cast<const uint2*>(&mask[r]);
#pragma unroll
      for (int j = 0; j < 8; ++j)
        cur[j] = *reinterpret_cast<const float4v*>(&hres[(size_t)(r + j) * HD + off]);
      r += 8;
      for (int c = 1; c < nfull; ++c) {
        mnxt = *reinterpret_cast<const uint2*>(&mask[r]);
#pragma unroll
        for (int j = 0; j < 8; ++j)
          nxt[j] = *reinterpret_cast<const float4v*>(&hres[(size_t)(r + j) * HD + off]);
        r += 8;
        {
          float4v s0 = 0.f, s1 = 0.f, s2 = 0.f, s3 = 0.f;
          if (mcur.x & 0x000000FFu) s0 += cur[0];
          if (mcur.x & 0x0000FF00u) s1 += cur[1];
          if (mcur.x & 0x00FF0000u) s2 += cur[2];
          if (mcur.x & 0xFF000000u) s3 += cur[3];
          if (mcur.y & 0x000000FFu) s0 += cur[4];
          if (mcur.y & 0x0000FF00u) s1 += cur[5];
          if (mcur.y & 0x00FF0000u) s2 += cur[6];
          if (mcur.y & 0xFF000000u) s3 += cur[7];
          racc += (s0 + s1) + (s2 + s3);
        }
        mcur = mnxt;
#pragma unroll
        for (int j = 0; j < 8; ++j) cur[j] = nxt[j];
      }
      {
        float4v s0 = 0.f, s1 = 0.f, s2 = 0.f, s3 = 0.f;
        if (mcur.x & 0x000000FFu) s0 += cur[0];
        if (mcur.x & 0x0000FF00u) s1 += cur[1];
        if (mcur.x & 0x00FF0000u) s2 += cur[2];
        if (mcur.x & 0xFF000000u) s3 += cur[3];
        if (mcur.y & 0x000000FFu) s0 += cur[4];
        if (mcur.y & 0x0000FF00u) s1 += cur[5];
        if (mcur.y & 0x00FF0000u) s2 += cur[6];
        if (mcur.y & 0xFF000000u) s3 += cur[7];
        racc += (s0 + s1) + (s2 + s3);
      }
    }
    for (; r < r1; ++r) {
      float4v v = *reinterpret_cast<const float4v*>(&hres[(size_t)r * HD + off]);
      if (mask[r]) racc += v;
    }
  }

  size_t o = (size_t)b * 768;
  {
    unsigned short h[4], l[4];
#pragma unroll
    for (int j = 0; j < 4; ++j) {
      h[j] = f2bf(acc[j]); l[j] = f2bf(acc[j] - bf2f(h[j]));
    }
    *reinterpret_cast<uint2*>(&pvh[o + off]) = *reinterpret_cast<uint2*>(h);
    *reinterpret_cast<uint2*>(&pvl[o + off]) = *reinterpret_cast<uint2*>(l);
  }
  *reinterpret_cast<uint2*>(&pvh[o + 256 + off]) =
      *reinterpret_cast<const uint2*>(&ehi[(size_t)wid[b] * 256 + off]);
  *reinterpret_cast<uint2*>(&pvl[o + 256 + off]) =
      *reinterpret_cast<const uint2*>(&elo[(size_t)wid[b] * 256 + off]);
  {
    unsigned short h[4], l[4];
#pragma unroll
    for (int j = 0; j < 4; ++j) {
      h[j] = f2bf(racc[j]); l[j] = f2bf(racc[j] - bf2f(h[j]));
    }
    *reinterpret_cast<uint2*>(&pvh[o + 512 + off]) = *reinterpret_cast<uint2*>(h);
    *reinterpret_cast<uint2*>(&pvl[o + 512 + off]) = *reinterpret_cast<uint2*>(l);
  }
}

// ---------------- MFMA 3-term MLP GEMM, 64x64 tile; bias(+relu) + split write ----------------
template <bool RELU, int K, int N>
__global__ __launch_bounds__(256) void mlp_gemm_kernel(
    const unsigned short* __restrict__ Ahg, const unsigned short* __restrict__ Alg,
    const unsigned short* __restrict__ Bhg, const unsigned short* __restrict__ Blg,
    const float* __restrict__ bias,
    unsigned short* __restrict__ Chi, unsigned short* __restrict__ Clo) {
  __shared__ __attribute__((aligned(16))) unsigned short Ahs[64][72];
  __shared__ __attribute__((aligned(16))) unsigned short Als[64][72];
  __shared__ __attribute__((aligned(16))) unsigned short Bhs[64][72];
  __shared__ __attribute__((aligned(16))) unsigned short Bls[64][72];

  int t = threadIdx.x;
  int bm = blockIdx.y * 64, bn = blockIdx.x * 64;
  int lane = t & 63, wv = t >> 6;
  int wm = wv >> 1, wn = wv & 1;
  int lr = lane & 15, lg = lane >> 4;
  float4v acc[2][2] = {};

  int srow = t >> 2, sc = (t & 3) * 16;

  for (int kb = 0; kb < K; kb += 64) {
    size_t ga = (size_t)(bm + srow) * K + kb + sc;
    size_t gb = (size_t)(bn + srow) * K + kb + sc;
    *reinterpret_cast<short8v*>(&Ahs[srow][sc]) = *reinterpret_cast<const short8v*>(&Ahg[ga]);
    *reinterpret_cast<short8v*>(&Ahs[srow][sc + 8]) = *reinterpret_cast<const short8v*>(&Ahg[ga + 8]);
    *reinterpret_cast<short8v*>(&Als[srow][sc]) = *reinterpret_cast<const short8v*>(&Alg[ga]);
    *reinterpret_cast<short8v*>(&Als[srow][sc + 8]) = *reinterpret_cast<const short8v*>(&Alg[ga + 8]);
    *reinterpret_cast<short8v*>(&Bhs[srow][sc]) = *reinterpret_cast<const short8v*>(&Bhg[gb]);
    *reinterpret_cast<short8v*>(&Bhs[srow][sc + 8]) = *reinterpret_cast<const short8v*>(&Bhg[gb + 8]);
    *reinterpret_cast<short8v*>(&Bls[srow][sc]) = *reinterpret_cast<const short8v*>(&Blg[gb]);
    *reinterpret_cast<short8v*>(&Bls[srow][sc + 8]) = *reinterpret_cast<const short8v*>(&Blg[gb + 8]);
    __syncthreads();

#pragma unroll
    for (int ks = 0; ks < 2; ++ks) {
      int ko = ks * 32 + lg * 8;
      short8v aH[2], aL[2], bH[2], bL[2];
#pragma unroll
      for (int f = 0; f < 2; ++f) {
        aH[f] = *reinterpret_cast<const short8v*>(&Ahs[wm * 32 + f * 16 + lr][ko]);
        aL[f] = *reinterpret_cast<const short8v*>(&Als[wm * 32 + f * 16 + lr][ko]);
        bH[f] = *reinterpret_cast<const short8v*>(&Bhs[wn * 32 + f * 16 + lr][ko]);
        bL[f] = *reinterpret_cast<const short8v*>(&Bls[wn * 32 + f * 16 + lr][ko]);
      }
#pragma unroll
      for (int mf = 0; mf < 2; ++mf)
#pragma unroll
        for (int nf = 0; nf < 2; ++nf) {
          acc[mf][nf] = __builtin_amdgcn_mfma_f32_16x16x32_bf16(
              aH[mf], bH[nf], acc[mf][nf], 0, 0, 0);
          acc[mf][nf] = __builtin_amdgcn_mfma_f32_16x16x32_bf16(
              aH[mf], bL[nf], acc[mf][nf], 0, 0, 0);
          acc[mf][nf] = __builtin_amdgcn_mfma_f32_16x16x32_bf16(
              aL[mf], bH[nf], acc[mf][nf], 0, 0, 0);
        }
    }
    __syncthreads();
  }

#pragma unroll
  for (int mf = 0; mf < 2; ++mf)
#pragma unroll
    for (int nf = 0; nf < 2; ++nf) {
      int col = bn + wn * 32 + nf * 16 + lr;
      float bv = bias[col];
#pragma unroll
      for (int rr = 0; rr < 4; ++rr) {
        int row = bm + wm * 32 + mf * 16 + lg * 4 + rr;
        float v = acc[mf][nf][rr] + bv;
        if (RELU) v = fmaxf(v, 0.f);
        unsigned short h = f2bf(v);
        Chi[(size_t)row * N + col] = h;
        Clo[(size_t)row * N + col] = f2bf(v - bf2f(h));
      }
    }
}

// ---------------- MFMA 3-term score GEMM (r12 structure) + bijective XCD swizzle ----------------
__global__ __launch_bounds__(256, 2) void score_gemm_kernel(
    const unsigned short* __restrict__ Ahg, const unsigned short* __restrict__ Alg,
    const unsigned short* __restrict__ Bhg, const unsigned short* __restrict__ Blg,
    float* __restrict__ C) {
  __shared__ __attribute__((aligned(16))) unsigned short Ah[128 * 64];
  __shared__ __attribute__((aligned(16))) unsigned short Al[128 * 64];
  __shared__ __attribute__((aligned(16))) unsigned short Bh[128 * 64];
  __shared__ __attribute__((aligned(16))) unsigned short Bl[128 * 64];

  int t = threadIdx.x;
  // T1: nwg = 32*63 = 2016, divisible by 8. XCD x (orig%8) gets contiguous swz
  // chunk [x*252,(x+1)*252): ~8 bn-panels + full A fit its 4MB L2.
  int orig = blockIdx.x + blockIdx.y * gridDim.x;
  int cpx = 2016 / 8;
  int swz = (orig & 7) * cpx + (orig >> 3);
  int bm = (swz & 31) * 128;          // bm fastest within chunk
  int bni = swz >> 5;
  int bn = bni * 128;

  int lane = t & 63, wv = t >> 6;
  int wm = wv >> 1, wn = wv & 1;      // 2x2 waves, each 64x64
  int lr = lane & 15, lg = lane >> 4;

  float4v acc[4][4] = {};

  int rsub = lane >> 3;               // row within 8-row chunk
  int cb = (lane & 7) * 16;           // byte col within 128B row slice

  for (int kb = 0; kb < 256; kb += 64) {
#pragma unroll
    for (int j = 0; j < 4; ++j) {
      int ch = wv * 4 + j;                       // 16 chunks of 8 rows
      int grow = ch * 8 + rsub;
      int scb = cb ^ ((grow & 7) << 4);          // pre-swizzled source col (bytes)
      size_t goA = (size_t)(bm + grow) * 256 + kb + (scb >> 1);
      size_t goB = (size_t)(bn + grow) * 256 + kb + (scb >> 1);
      unsigned lo = ch * 512 + lane * 8;         // linear dest
      gl16(&Ahg[goA], &Ah[lo]);
      gl16(&Alg[goA], &Al[lo]);
      gl16(&Bhg[goB], &Bh[lo]);
      gl16(&Blg[goB], &Bl[lo]);
    }
    __syncthreads();

#pragma unroll
    for (int ks = 0; ks < 2; ++ks) {
      int bo = (ks * 32 + lg * 8) * 2;           // byte offset within row
      short8v aH[4], aL[4], bH[4], bL[4];
#pragma unroll
      for (int f = 0; f < 4; ++f) {
        int ra = wm * 64 + f * 16 + lr;
        int rb2 = wn * 64 + f * 16 + lr;
        int oa = ra * 128 + (bo ^ ((ra & 7) << 4));
        int ob2 = rb2 * 128 + (bo ^ ((rb2 & 7) << 4));
        aH[f] = *reinterpret_cast<const short8v*>((const char*)Ah + oa);
        aL[f] = *reinterpret_cast<const short8v*>((const char*)Al + oa);
        bH[f] = *reinterpret_cast<const short8v*>((const char*)Bh + ob2);
        bL[f] = *reinterpret_cast<const short8v*>((const char*)Bl + ob2);
      }
#pragma unroll
      for (int mf = 0; mf < 4; ++mf)
#pragma unroll
        for (int nf = 0; nf < 4; ++nf) {
          acc[mf][nf] = __builtin_amdgcn_mfma_f32_16x16x32_bf16(
              aH[mf], bH[nf], acc[mf][nf], 0, 0, 0);
          acc[mf][nf] = __builtin_amdgcn_mfma_f32_16x16x32_bf16(
              aH[mf], bL[nf], acc[mf][nf], 0, 0, 0);
          acc[mf][nf] = __builtin_amdgcn_mfma_f32_16x16x32_bf16(
              aL[mf], bH[nf], acc[mf][nf], 0, 0, 0);
        }
    }
    __syncthreads();
  }

  // C/D layout: col = lane&15, row = (lane>>4)*4 + reg  [m89]
#pragma unroll
  for (int mf = 0; mf < 4; ++mf)
#pragma unroll
    for (int nf = 0; nf < 4; ++nf) {
      int col = bn + wn * 64 + nf * 16 + lr;
      if (col < VV) {
#pragma unroll
        for (int rr = 0; rr < 4; ++rr) {
          int row = bm + wm * 64 + mf * 16 + lg * 4 + rr;
          C[(size_t)row * VV + col] = acc[mf][nf][rr];
        }
      }
    }
}

// ---------------- single-pass top-5 (float4 loads) + threefry pick ----------------
#define BETTER(av, ai, bv, bi) ((av) > (bv) || ((av) == (bv) && (ai) < (bi)))

__global__ __launch_bounds__(256) void topk_kernel(
    const float* __restrict__ scores, float* __restrict__ preds,
    unsigned k1a, unsigned k1b, unsigned k2a, unsigned k2b) {
  int lane = threadIdx.x & 63;
  int row = (blockIdx.x << 2) + (threadIdx.x >> 6);
  const float* s = scores + (size_t)row * VV;

  const float NEG = -__builtin_huge_valf();
  float v0 = NEG, v1 = NEG, v2 = NEG, v3 = NEG, v4 = NEG;
  int i0 = 0x7FFFFFFF, i1 = 0x7FFFFFFF, i2 = 0x7FFFFFFF, i3 = 0x7FFFFFFF, i4 = 0x7FFFFFFF;

#define INSERT(val, vidx)                                        \
  if (BETTER(val, vidx, v4, i4)) {                               \
    if (BETTER(val, vidx, v3, i3)) { v4 = v3; i4 = i3;           \
      if (BETTER(val, vidx, v2, i2)) { v3 = v2; i3 = i2;         \
        if (BETTER(val, vidx, v1, i1)) { v2 = v1; i2 = i1;       \
          if (BETTER(val, vidx, v0, i0)) { v1 = v0; i1 = i0;     \
            v0 = val; i0 = vidx; } else { v1 = val; i1 = vidx; } \
        } else { v2 = val; i2 = vidx; }                          \
      } else { v3 = val; i3 = vidx; }                            \
    } else { v4 = val; i4 = vidx; }                              \
  }

  // vector body: 31 chunks of 256 (lane*4), ascending index within lane
  for (int cidx = 0; cidx < 31; ++cidx) {
    int base = cidx * 256 + lane * 4;
    float4 q = *reinterpret_cast<const float4*>(&s[base]);
    INSERT(q.x, base + 0);
    INSERT(q.y, base + 1);
    INSERT(q.z, base + 2);
    INSERT(q.w, base + 3);
  }
  // tail 7936..8000
  for (int v = 7936 + lane; v < VV; v += 64) {
    float val = s[v];
    INSERT(val, v);
  }
#undef INSERT

  int sel0, sel1, sel2, sel3, sel4;
#pragma unroll
  for (int p = 0; p < TOPKN; ++p) {
    float bv = v0; int bi = i0;
#pragma unroll
    for (int off = 32; off > 0; off >>= 1) {
      float ov = __shfl_xor(bv, off);
      int   oi = __shfl_xor(bi, off);
      if (BETTER(ov, oi, bv, bi)) { bv = ov; bi = oi; }
    }
    if (p == 0) sel0 = bi; else if (p == 1) sel1 = bi; else if (p == 2) sel2 = bi;
    else if (p == 3) sel3 = bi; else sel4 = bi;
    if (bi == i0) {
      v0 = v1; i0 = i1; v1 = v2; i1 = i2; v2 = v3; i2 = i3; v3 = v4; i3 = i4;
      v4 = NEG; i4 = 0x7FFFFFFF;
    }
  }

  if (lane == 0) {
    unsigned i = (unsigned)row;
    unsigned h0, h1, l0, l1;
    threefry2x32(k1a, k1b, 0u, i, h0, h1);
    threefry2x32(k2a, k2b, 0u, i, l0, l1);
    unsigned idx = (((h0 ^ h1) % 5u) + ((l0 ^ l1) % 5u)) % 5u;
    int pick = (idx == 0) ? sel0 : (idx == 1) ? sel1 : (idx == 2) ? sel2
             : (idx == 3) ? sel3 : sel4;
    preds[row] = (float)pick;
  }
}

extern "C" void kernel_launch(void* const* d_in, const int* in_sizes, int n_in,
                              void* d_out, int out_size, void* d_ws, size_t ws_size,
                              hipStream_t stream) {
  const float* hcf  = (const float*)d_in[0];
  const float* pcf  = (const float*)d_in[1];
  const int*   wid  = (const int*)d_in[2];
  const int*   ab   = (const int*)d_in[3];
  const float* hres = (const float*)d_in[4];
  const float* rpos = (const float*)d_in[5];
  const int*   rb   = (const int*)d_in[6];
  const float* emb  = (const float*)d_in[7];
  const float* w1   = (const float*)d_in[8];
  const float* bb1  = (const float*)d_in[9];
  const float* w2   = (const float*)d_in[10];
  const float* bb2  = (const float*)d_in[11];

  float* out    = (float*)d_out;
  float* scores = out;
  float* preds  = out + (size_t)BSZ * VV;

  // Intermediates in d_out's dead region (all consumed before scores written):
  char* ob = (char*)d_out;
  unsigned short* pvh  = (unsigned short*)(ob);               // 6 MB
  unsigned short* pvl  = (unsigned short*)(ob + 0x600000);    // 6 MB
  unsigned short* hh   = (unsigned short*)(ob + 0xC00000);    // 2 MB
  unsigned short* hl   = (unsigned short*)(ob + 0xE00000);    // 2 MB
  unsigned short* w1th = (unsigned short*)(ob + 0x1000000);   // 384 KB
  unsigned short* w1tl = (unsigned short*)(ob + 0x1060000);   // 384 KB
  unsigned short* w2th = (unsigned short*)(ob + 0x10C0000);   // 128 KB
  unsigned short* w2tl = (unsigned short*)(ob + 0x10E0000);   // 128 KB

  // d_ws:
  char* ws = (char*)d_ws;
  int*            bounds = (int*)(ws);                        // 32 KB
  unsigned char*  mask   = (unsigned char*)(ws + 0x10000);    // 256 KB
  unsigned short* mh_hi  = (unsigned short*)(ws + 0x100000);  // 2 MB
  unsigned short* mh_lo  = (unsigned short*)(ws + 0x300000);  // 2 MB
  unsigned short* emb_hi = (unsigned short*)(ws + 0x500000);  // 4.03 MB
  unsigned short* emb_lo = (unsigned short*)(ws + 0x900000);  // 4.03 MB

  prep_kernel<<<33 + 2016 + 768 + 256, 256, 0, stream>>>(
      ab, rb, bounds, emb, emb_hi, emb_lo, w1, w1th, w1tl, w2, w2th, w2tl);

  mask_kernel<<<BSZ / 4, 256, 0, stream>>>(pcf, rpos, bounds, mask);

  fuse_seg_kernel<<<BSZ / 4, 256, 0, stream>>>(
      hcf, wid, hres, mask, emb_hi, emb_lo, bounds, pvh, pvl);

  mlp_gemm_kernel<true, 768, 256><<<dim3(4, 64), 256, 0, stream>>>(
      pvh, pvl, w1th, w1tl, bb1, hh, hl);
  mlp_gemm_kernel<false, 256, 256><<<dim3(4, 64), 256, 0, stream>>>(
      hh, hl, w2th, w2tl, bb2, mh_hi, mh_lo);

  score_gemm_kernel<<<dim3(BSZ / 128, EPAD / 128), 256, 0, stream>>>(
      mh_hi, mh_lo, emb_hi, emb_lo, scores);

  unsigned k1a, k1b, k2a, k2b;
  threefry2x32(0u, 1u, 0u, 0u, k1a, k1b);
  threefry2x32(0u, 1u, 0u, 1u, k2a, k2b);
  topk_kernel<<<BSZ / 4, 256, 0, stream>>>(scores, preds, k1a, k1b, k2a, k2b);
}